// Round 1
// baseline (1049.317 us; speedup 1.0000x reference)
//
#include <hip/hip_runtime.h>
#include <hip/hip_bf16.h>
#include <math.h>

#define Tt 4096
#define Dd 1024
#define Ff 2048
#define Ee 8

typedef short bf16x8 __attribute__((ext_vector_type(8)));
typedef float f32x4 __attribute__((ext_vector_type(4)));

__device__ __forceinline__ unsigned short f2bf(float f) {
  union { float f; unsigned u; } v; v.f = f;
  unsigned r = v.u + 0x7fffu + ((v.u >> 16) & 1u);
  return (unsigned short)(r >> 16);
}

// ---------------- Router: 1 wave per token ----------------
__global__ __launch_bounds__(64) void router_kernel(
    const float* __restrict__ x, const float* __restrict__ gw,
    float* __restrict__ logits, float* __restrict__ combine)
{
  int t = blockIdx.x;
  int lane = threadIdx.x;
  const float* xr = x + (size_t)t * Dd;
  float xv[16];
#pragma unroll
  for (int i = 0; i < 4; ++i) {
    float4 v = *reinterpret_cast<const float4*>(xr + lane * 16 + i * 4);
    xv[i*4+0] = v.x; xv[i*4+1] = v.y; xv[i*4+2] = v.z; xv[i*4+3] = v.w;
  }
  float sums[Ee];
#pragma unroll
  for (int e = 0; e < Ee; ++e) {
    const float* gr = gw + (size_t)e * Dd + lane * 16;
    float s = 0.f;
#pragma unroll
    for (int i = 0; i < 4; ++i) {
      float4 g = *reinterpret_cast<const float4*>(gr + i * 4);
      s += xv[i*4+0]*g.x + xv[i*4+1]*g.y + xv[i*4+2]*g.z + xv[i*4+3]*g.w;
    }
#pragma unroll
    for (int o = 32; o > 0; o >>= 1) s += __shfl_xor(s, o);
    sums[e] = s;
  }
  if (lane < Ee) logits[(size_t)t * Ee + lane] = sums[lane];
  // top-2 (stable: lower index wins ties, matching lax.top_k)
  int i1 = 0; float m1 = sums[0];
#pragma unroll
  for (int e = 1; e < Ee; ++e) if (sums[e] > m1) { m1 = sums[e]; i1 = e; }
  int i2 = -1; float m2 = -__builtin_inff();
#pragma unroll
  for (int e = 0; e < Ee; ++e) if (e != i1 && sums[e] > m2) { m2 = sums[e]; i2 = e; }
  // renormalized top-2 softmax == softmax over the two selected logits
  float wa = 1.f / (1.f + expf(m2 - m1));
  float wb = 1.f - wa;
  if (lane < Ee) {
    float w = (lane == i1) ? wa : ((lane == i2) ? wb : 0.f);
    combine[(size_t)t * Ee + lane] = w;
  }
}

// ---------------- GEMM: 128x128 tile, BK=32, bf16 MFMA ----------------
// MODE 0: C = silu(A @ B)            (up-proj, C = h1, f32)
// MODE 1: C (+)= combine[row,e] * (A @ B)   (down-proj into out)
template<int MODE, int N_, int K_>
__global__ __launch_bounds__(256) void gemm_kernel(
    const float* __restrict__ A, const float* __restrict__ Bg,
    float* __restrict__ C, const float* __restrict__ combine,
    int expert, int first)
{
  constexpr int BM = 128, BN = 128, BK = 32, LDT = 40; // LDT=40: rows 80B -> 16B-aligned b128 reads, <=2-way bank conflicts
  __shared__ unsigned short Al[BM * LDT];
  __shared__ unsigned short Bl[BN * LDT];
  const int tid  = threadIdx.x;
  const int lane = tid & 63;
  const int wave = tid >> 6;
  const int wr = wave >> 1, wc = wave & 1;
  const int m0 = blockIdx.y * BM;
  const int n0 = blockIdx.x * BN;

  f32x4 acc[4][4] = {};

  for (int k0 = 0; k0 < K_; k0 += BK) {
    // stage A tile (128x32 f32 -> bf16), 1024 float4, 4 per thread
#pragma unroll
    for (int i = 0; i < 4; ++i) {
      int f = tid + 256 * i;
      int row = f >> 3;
      int c4 = (f & 7) << 2;
      float4 v = *reinterpret_cast<const float4*>(A + (size_t)(m0 + row) * K_ + k0 + c4);
      ushort4 b;
      b.x = f2bf(v.x); b.y = f2bf(v.y); b.z = f2bf(v.z); b.w = f2bf(v.w);
      *reinterpret_cast<ushort4*>(&Al[row * LDT + c4]) = b;
    }
    // stage B tile transposed: Bg[k0..k0+32, n0..n0+128] -> Bl[n][k]
    {
      int n  = tid & 127;
      int kb = (tid >> 7) << 4;
      const float* bp = Bg + (size_t)(k0 + kb) * N_ + n0 + n;
      unsigned short tmp[16];
#pragma unroll
      for (int kk = 0; kk < 16; ++kk)
        tmp[kk] = f2bf(bp[(size_t)kk * N_]);
      unsigned short* p = &Bl[n * LDT + kb];
#pragma unroll
      for (int i = 0; i < 4; ++i) {
        ushort4 b;
        b.x = tmp[i*4+0]; b.y = tmp[i*4+1]; b.z = tmp[i*4+2]; b.w = tmp[i*4+3];
        *reinterpret_cast<ushort4*>(p + i * 4) = b;
      }
    }
    __syncthreads();

    bf16x8 af[4], bfr[4];
    const int kq  = (lane >> 4) << 3;
    const int r16 = lane & 15;
#pragma unroll
    for (int m = 0; m < 4; ++m)
      af[m] = *reinterpret_cast<const bf16x8*>(&Al[(wr*64 + m*16 + r16) * LDT + kq]);
#pragma unroll
    for (int n = 0; n < 4; ++n)
      bfr[n] = *reinterpret_cast<const bf16x8*>(&Bl[(wc*64 + n*16 + r16) * LDT + kq]);
#pragma unroll
    for (int m = 0; m < 4; ++m)
#pragma unroll
      for (int n = 0; n < 4; ++n)
        acc[m][n] = __builtin_amdgcn_mfma_f32_16x16x32_bf16(af[m], bfr[n], acc[m][n], 0, 0, 0);
    __syncthreads();
  }

  // epilogue: C/D layout col=lane&15, row=(lane>>4)*4+reg
  const int col0 = n0 + wc * 64 + (lane & 15);
  const int rb   = m0 + wr * 64 + ((lane >> 4) << 2);
#pragma unroll
  for (int m = 0; m < 4; ++m) {
#pragma unroll
    for (int r = 0; r < 4; ++r) {
      int row = rb + m * 16 + r;
      if (MODE == 0) {
#pragma unroll
        for (int n = 0; n < 4; ++n) {
          float v = acc[m][n][r];
          v = v / (1.f + expf(-v));                 // silu
          C[(size_t)row * N_ + col0 + n * 16] = v;
        }
      } else {
        float w = combine[(size_t)row * Ee + expert];
        if (first) {
#pragma unroll
          for (int n = 0; n < 4; ++n)
            C[(size_t)row * N_ + col0 + n * 16] = w * acc[m][n][r];
        } else {
#pragma unroll
          for (int n = 0; n < 4; ++n)
            C[(size_t)row * N_ + col0 + n * 16] += w * acc[m][n][r];
        }
      }
    }
  }
}

extern "C" void kernel_launch(void* const* d_in, const int* in_sizes, int n_in,
                              void* d_out, int out_size, void* d_ws, size_t ws_size,
                              hipStream_t stream)
{
  const float* x  = (const float*)d_in[0];   // [2,2048,1024]
  const float* gw = (const float*)d_in[1];   // [8,1024]
  const float* w1 = (const float*)d_in[2];   // [8,1024,2048]
  const float* w2 = (const float*)d_in[3];   // [8,2048,1024]
  float* out     = (float*)d_out;            // [T*D]
  float* logits  = out + (size_t)Tt * Dd;    // [T*E]
  float* combine = (float*)d_ws;             // [T*E] f32
  float* h1      = combine + (size_t)Tt * Ee; // [chunk*F] f32

  router_kernel<<<Tt, 64, 0, stream>>>(x, gw, logits, combine);

  // adaptive chunking in case ws is small (need chunk*F*4 bytes for h1)
  size_t cb = (size_t)Tt * Ee * sizeof(float);
  size_t avail = ws_size > cb ? (ws_size - cb) : 0;
  long maxrows = (long)(avail / ((size_t)Ff * sizeof(float)));
  int chunk = (maxrows >= Tt) ? Tt : (int)((maxrows / 128) * 128);
  if (chunk < 128) chunk = 128;

  for (int c0 = 0; c0 < Tt; c0 += chunk) {
    int rows = (Tt - c0) < chunk ? (Tt - c0) : chunk;
    for (int e = 0; e < Ee; ++e) {
      gemm_kernel<0, Ff, Dd><<<dim3(Ff/128, rows/128), 256, 0, stream>>>(
          x + (size_t)c0 * Dd, w1 + (size_t)e * Dd * Ff, h1, nullptr, e, 0);
      gemm_kernel<1, Dd, Ff><<<dim3(Dd/128, rows/128), 256, 0, stream>>>(
          h1, w2 + (size_t)e * Ff * Dd, out + (size_t)c0 * Dd,
          combine + (size_t)c0 * Ee, e, (e == 0) ? 1 : 0);
    }
  }
}

// Round 2
// 390.711 us; speedup vs baseline: 2.6857x; 2.6857x over previous
//
#include <hip/hip_runtime.h>
#include <hip/hip_bf16.h>
#include <math.h>

#define Tt 4096
#define Dd 1024
#define Ff 2048
#define Ee 8

typedef unsigned short u16;
typedef short bf16x8 __attribute__((ext_vector_type(8)));
typedef unsigned short u16x8 __attribute__((ext_vector_type(8)));
typedef float f32x4 __attribute__((ext_vector_type(4)));

__device__ __forceinline__ u16 f2bf(float f) {
  union { float f; unsigned u; } v; v.f = f;
  unsigned r = v.u + 0x7fffu + ((v.u >> 16) & 1u);
  return (u16)(r >> 16);
}

// ---------------- Router: 1 wave per token ----------------
// sparse=1: writes logits, per-token top2 (sel/topw), and group counts.
// sparse=0: writes logits and dense combine weights (fallback path).
__global__ __launch_bounds__(64) void router_kernel(
    const float* __restrict__ x, const float* __restrict__ gw,
    float* __restrict__ logits, float* __restrict__ combine,
    int* __restrict__ sel, float* __restrict__ topw, int* __restrict__ cnt,
    int sparse)
{
  int t = blockIdx.x;
  int lane = threadIdx.x;
  const float* xr = x + (size_t)t * Dd;
  float xv[16];
#pragma unroll
  for (int i = 0; i < 4; ++i) {
    float4 v = *reinterpret_cast<const float4*>(xr + lane * 16 + i * 4);
    xv[i*4+0] = v.x; xv[i*4+1] = v.y; xv[i*4+2] = v.z; xv[i*4+3] = v.w;
  }
  float sums[Ee];
#pragma unroll
  for (int e = 0; e < Ee; ++e) {
    const float* gr = gw + (size_t)e * Dd + lane * 16;
    float s = 0.f;
#pragma unroll
    for (int i = 0; i < 4; ++i) {
      float4 g = *reinterpret_cast<const float4*>(gr + i * 4);
      s += xv[i*4+0]*g.x + xv[i*4+1]*g.y + xv[i*4+2]*g.z + xv[i*4+3]*g.w;
    }
#pragma unroll
    for (int o = 32; o > 0; o >>= 1) s += __shfl_xor(s, o);
    sums[e] = s;
  }
  if (lane < Ee) logits[(size_t)t * Ee + lane] = sums[lane];
  int i1 = 0; float m1 = sums[0];
#pragma unroll
  for (int e = 1; e < Ee; ++e) if (sums[e] > m1) { m1 = sums[e]; i1 = e; }
  int i2 = -1; float m2 = -__builtin_inff();
#pragma unroll
  for (int e = 0; e < Ee; ++e) if (e != i1 && sums[e] > m2) { m2 = sums[e]; i2 = e; }
  float wa = 1.f / (1.f + expf(m2 - m1));   // renormalized top-2 softmax
  float wb = 1.f - wa;
  if (sparse) {
    if (lane == 0) {
      sel[2*t] = i1; sel[2*t+1] = i2;
      topw[2*t] = wa; topw[2*t+1] = wb;
      atomicAdd(&cnt[i1], 1);        // group g = e + 8*k
      atomicAdd(&cnt[8 + i2], 1);
    }
  } else {
    if (lane < Ee) {
      float w = (lane == i1) ? wa : ((lane == i2) ? wb : 0.f);
      combine[(size_t)t * Ee + lane] = w;
    }
  }
}

// ---------------- list building ----------------
__global__ __launch_bounds__(64) void zero_meta_kernel(int* meta) {
  if (threadIdx.x < 64) meta[threadIdx.x] = 0;
}
__global__ __launch_bounds__(64) void offsets_kernel(int* meta) {
  if (threadIdx.x == 0) {
    int s = 0;
    for (int g = 0; g < 16; ++g) { meta[32 + g] = s; s += meta[g]; }
  }
}
__global__ __launch_bounds__(256) void assign_kernel(
    const int* __restrict__ sel, const float* __restrict__ topw,
    int* __restrict__ meta, int* __restrict__ list, float* __restrict__ wgt)
{
  int t = blockIdx.x * 256 + threadIdx.x;
  if (t >= Tt) return;
#pragma unroll
  for (int k = 0; k < 2; ++k) {
    int g = sel[2*t + k] + 8*k;
    int pos = atomicAdd(&meta[16 + g], 1);
    int slot = meta[32 + g] + pos;
    list[slot] = t;
    wgt[slot] = topw[2*t + k];
  }
}

// ---------------- conversions ----------------
__global__ __launch_bounds__(256) void cvt_bf16_kernel(
    const float* __restrict__ in, u16* __restrict__ out, int n4)
{
  int i = blockIdx.x * 256 + threadIdx.x;
  if (i >= n4) return;
  float4 v = reinterpret_cast<const float4*>(in)[i];
  ushort4 b;
  b.x = f2bf(v.x); b.y = f2bf(v.y); b.z = f2bf(v.z); b.w = f2bf(v.w);
  reinterpret_cast<ushort4*>(out)[i] = b;
}

// transpose [R][C] f32 -> [C][R] bf16, per expert (blockIdx.z)
__global__ __launch_bounds__(256) void transpose_bf16_kernel(
    const float* __restrict__ in, u16* __restrict__ out, int R, int C)
{
  __shared__ u16 st[64][65];
  const size_t eoff = (size_t)blockIdx.z * R * C;
  const float* ip = in + eoff;
  u16* op = out + eoff;
  int r0 = blockIdx.y * 64, c0 = blockIdx.x * 64;
  int t = threadIdx.x;
  int rr = t >> 2;
  int cb = (t & 3) * 16;
#pragma unroll
  for (int i = 0; i < 4; ++i) {
    float4 v = *reinterpret_cast<const float4*>(ip + (size_t)(r0 + rr) * C + c0 + cb + i * 4);
    st[rr][cb + i*4 + 0] = f2bf(v.x);
    st[rr][cb + i*4 + 1] = f2bf(v.y);
    st[rr][cb + i*4 + 2] = f2bf(v.z);
    st[rr][cb + i*4 + 3] = f2bf(v.w);
  }
  __syncthreads();
#pragma unroll
  for (int i = 0; i < 4; ++i) {
    ushort4 b;
    b.x = st[cb + i*4 + 0][rr];
    b.y = st[cb + i*4 + 1][rr];
    b.z = st[cb + i*4 + 2][rr];
    b.w = st[cb + i*4 + 3][rr];
    *reinterpret_cast<ushort4*>(op + (size_t)(c0 + rr) * R + r0 + cb + i * 4) = b;
  }
}

// ---------------- grouped GEMM ----------------
// MODE 0: h1[slot] = silu(xb[list[slot]] @ w1T[e]^T)   (BM=128, N=F, K=D)
// MODE 1: out[list[slot]]  = wgt[slot] * (h1[slot] @ w2T[e]^T)   (groups 0-7)
// MODE 2: out[list[slot]] += wgt[slot] * (h1[slot] @ w2T[e]^T)   (groups 8-15)
// Bbase layout: [e][n][k] bf16 (k contiguous).
template<int BM, int MODE, int N_, int K_>
__global__ __launch_bounds__(256) void gemm_g(
    const u16* __restrict__ Abase, const u16* __restrict__ Bbase,
    void* __restrict__ Cout, const int* __restrict__ meta,
    const int* __restrict__ list, const float* __restrict__ wgt)
{
  constexpr int BN = 128, LDT = 40;   // LDT=40 shorts: 80B rows (16B aligned), conflict-light
  constexpr int WGR = BM / 64;        // wave grid rows: 2 (BM=128) or 1 (BM=64)
  constexpr int WGC = 4 / WGR;        // wave grid cols: 2 or 4
  constexpr int WN  = BN / WGC;       // per-wave N: 64 or 32
  constexpr int NFR = WN / 16;        // B frags: 4 or 2
  constexpr int AJ  = BM / 64;        // A staging chunks per thread

  __shared__ u16 Al[BM * LDT];
  __shared__ u16 Bl[BN * LDT];

  const int g   = blockIdx.z + ((MODE == 2) ? 8 : 0);
  const int e   = g & 7;
  const int cnt = meta[g];
  const int rb  = blockIdx.y;
  if (rb * BM >= cnt) return;
  const int off = meta[32 + g];

  const int tid  = threadIdx.x;
  const int lane = tid & 63;
  const int wave = tid >> 6;
  const int wr   = (WGR == 2) ? (wave >> 1) : 0;
  const int wc   = (WGR == 2) ? (wave & 1) : wave;
  const int n0   = blockIdx.x * BN;
  const int kp   = tid & 3;

  // per-thread A source rows (gathered for MODE 0), hoisted out of K-loop
  size_t asrc[AJ];
  int alds[AJ];
#pragma unroll
  for (int j = 0; j < AJ; ++j) {
    int idx = tid + 256 * j;
    int row = idx >> 2;
    int i = rb * BM + row;
    if (i >= cnt) i = cnt - 1;
    int srow = (MODE == 0) ? list[off + i] : (off + i);
    asrc[j] = (size_t)srow * K_ + kp * 8;
    alds[j] = row * LDT + kp * 8;
  }
  size_t bsrc[2];
  int blds[2];
#pragma unroll
  for (int j = 0; j < 2; ++j) {
    int idx = tid + 256 * j;
    int row = idx >> 2;
    bsrc[j] = ((size_t)e * N_ + n0 + row) * K_ + kp * 8;
    blds[j] = row * LDT + kp * 8;
  }

  f32x4 acc[4][NFR] = {};
  const int r16 = lane & 15;
  const int kq  = (lane >> 4) * 8;

  for (int k0 = 0; k0 < K_; k0 += 32) {
#pragma unroll
    for (int j = 0; j < AJ; ++j) {
      u16x8 v = *reinterpret_cast<const u16x8*>(Abase + asrc[j] + k0);
      *reinterpret_cast<u16x8*>(&Al[alds[j]]) = v;
    }
#pragma unroll
    for (int j = 0; j < 2; ++j) {
      u16x8 v = *reinterpret_cast<const u16x8*>(Bbase + bsrc[j] + k0);
      *reinterpret_cast<u16x8*>(&Bl[blds[j]]) = v;
    }
    __syncthreads();

    bf16x8 af[4], bfv[NFR];
#pragma unroll
    for (int m = 0; m < 4; ++m)
      af[m] = *reinterpret_cast<const bf16x8*>(&Al[(wr*64 + m*16 + r16) * LDT + kq]);
#pragma unroll
    for (int n = 0; n < NFR; ++n)
      bfv[n] = *reinterpret_cast<const bf16x8*>(&Bl[(wc*WN + n*16 + r16) * LDT + kq]);
#pragma unroll
    for (int m = 0; m < 4; ++m)
#pragma unroll
      for (int n = 0; n < NFR; ++n)
        acc[m][n] = __builtin_amdgcn_mfma_f32_16x16x32_bf16(af[m], bfv[n], acc[m][n], 0, 0, 0);
    __syncthreads();
  }

  // epilogue: C/D frag layout col=lane&15, row=(lane>>4)*4+reg
  const int colb = n0 + wc * WN + r16;
  const int rb4  = wr * 64 + ((lane >> 4) << 2);
#pragma unroll
  for (int m = 0; m < 4; ++m) {
#pragma unroll
    for (int r = 0; r < 4; ++r) {
      int i = rb * BM + rb4 + m * 16 + r;
      if (i >= cnt) continue;
      if (MODE == 0) {
        u16* hp = (u16*)Cout + (size_t)(off + i) * N_;
#pragma unroll
        for (int n = 0; n < NFR; ++n) {
          float v = acc[m][n][r];
          v = v / (1.f + expf(-v));            // silu
          hp[colb + n * 16] = f2bf(v);
        }
      } else {
        int   tok = list[off + i];
        float w   = wgt[off + i];
        float* o = (float*)Cout + (size_t)tok * N_;
#pragma unroll
        for (int n = 0; n < NFR; ++n) {
          float v = w * acc[m][n][r];
          if (MODE == 1) o[colb + n * 16] = v;
          else           o[colb + n * 16] += v;
        }
      }
    }
  }
}

// ---------------- dense fallback GEMM (round-1, known-good) ----------------
template<int MODE, int N_, int K_>
__global__ __launch_bounds__(256) void gemm_dense(
    const float* __restrict__ A, const float* __restrict__ Bg,
    float* __restrict__ C, const float* __restrict__ combine,
    int expert, int first)
{
  constexpr int BM = 128, BN = 128, BK = 32, LDT = 40;
  __shared__ u16 Al[BM * LDT];
  __shared__ u16 Bl[BN * LDT];
  const int tid  = threadIdx.x;
  const int lane = tid & 63;
  const int wave = tid >> 6;
  const int wr = wave >> 1, wc = wave & 1;
  const int m0 = blockIdx.y * BM;
  const int n0 = blockIdx.x * BN;
  f32x4 acc[4][4] = {};
  for (int k0 = 0; k0 < K_; k0 += BK) {
#pragma unroll
    for (int i = 0; i < 4; ++i) {
      int f = tid + 256 * i;
      int row = f >> 3;
      int c4 = (f & 7) << 2;
      float4 v = *reinterpret_cast<const float4*>(A + (size_t)(m0 + row) * K_ + k0 + c4);
      ushort4 b;
      b.x = f2bf(v.x); b.y = f2bf(v.y); b.z = f2bf(v.z); b.w = f2bf(v.w);
      *reinterpret_cast<ushort4*>(&Al[row * LDT + c4]) = b;
    }
    {
      int n  = tid & 127;
      int kb = (tid >> 7) << 4;
      const float* bp = Bg + (size_t)(k0 + kb) * N_ + n0 + n;
      u16 tmp[16];
#pragma unroll
      for (int kk = 0; kk < 16; ++kk)
        tmp[kk] = f2bf(bp[(size_t)kk * N_]);
      u16* p = &Bl[n * LDT + kb];
#pragma unroll
      for (int i = 0; i < 4; ++i) {
        ushort4 b;
        b.x = tmp[i*4+0]; b.y = tmp[i*4+1]; b.z = tmp[i*4+2]; b.w = tmp[i*4+3];
        *reinterpret_cast<ushort4*>(p + i * 4) = b;
      }
    }
    __syncthreads();
    bf16x8 af[4], bfr[4];
    const int kq  = (lane >> 4) << 3;
    const int r16 = lane & 15;
#pragma unroll
    for (int m = 0; m < 4; ++m)
      af[m] = *reinterpret_cast<const bf16x8*>(&Al[(wr*64 + m*16 + r16) * LDT + kq]);
#pragma unroll
    for (int n = 0; n < 4; ++n)
      bfr[n] = *reinterpret_cast<const bf16x8*>(&Bl[(wc*64 + n*16 + r16) * LDT + kq]);
#pragma unroll
    for (int m = 0; m < 4; ++m)
#pragma unroll
      for (int n = 0; n < 4; ++n)
        acc[m][n] = __builtin_amdgcn_mfma_f32_16x16x32_bf16(af[m], bfr[n], acc[m][n], 0, 0, 0);
    __syncthreads();
  }
  const int col0 = n0 + wc * 64 + (lane & 15);
  const int rbs  = m0 + wr * 64 + ((lane >> 4) << 2);
#pragma unroll
  for (int m = 0; m < 4; ++m) {
#pragma unroll
    for (int r = 0; r < 4; ++r) {
      int row = rbs + m * 16 + r;
      if (MODE == 0) {
#pragma unroll
        for (int n = 0; n < 4; ++n) {
          float v = acc[m][n][r];
          v = v / (1.f + expf(-v));
          C[(size_t)row * N_ + col0 + n * 16] = v;
        }
      } else {
        float w = combine[(size_t)row * Ee + expert];
        if (first) {
#pragma unroll
          for (int n = 0; n < 4; ++n)
            C[(size_t)row * N_ + col0 + n * 16] = w * acc[m][n][r];
        } else {
#pragma unroll
          for (int n = 0; n < 4; ++n)
            C[(size_t)row * N_ + col0 + n * 16] += w * acc[m][n][r];
        }
      }
    }
  }
}

extern "C" void kernel_launch(void* const* d_in, const int* in_sizes, int n_in,
                              void* d_out, int out_size, void* d_ws, size_t ws_size,
                              hipStream_t stream)
{
  const float* x  = (const float*)d_in[0];   // [2,2048,1024]
  const float* gw = (const float*)d_in[1];   // [8,1024]
  const float* w1 = (const float*)d_in[2];   // [8,1024,2048]
  const float* w2 = (const float*)d_in[3];   // [8,2048,1024]
  float* out    = (float*)d_out;
  float* logits = out + (size_t)Tt * Dd;

  // sparse-path ws layout
  int*   meta = (int*)d_ws;                       // 64 ints: cnt[16], cur[16], offs[16]
  int*   sel  = meta + 64;                        // [T*2]
  float* topw = (float*)(sel + 2 * Tt);           // [T*2]
  int*   list = (int*)(topw + 2 * Tt);            // [8192]
  float* wgt  = (float*)(list + 2 * Tt);          // [8192]
  u16*   xb   = (u16*)((char*)d_ws + 262144);                         // 8 MB
  u16*   h1   = (u16*)((char*)d_ws + 262144 + 8388608);               // 32 MB
  u16*   wT   = (u16*)((char*)d_ws + 262144 + 8388608 + 33554432);    // 33.5 MB (w1T then w2T)
  const size_t NEED = 262144ull + 8388608ull + 33554432ull + 33554432ull;

  if (ws_size >= NEED) {
    zero_meta_kernel<<<1, 64, 0, stream>>>(meta);
    router_kernel<<<Tt, 64, 0, stream>>>(x, gw, logits, nullptr, sel, topw, meta, 1);
    offsets_kernel<<<1, 64, 0, stream>>>(meta);
    assign_kernel<<<Tt / 256, 256, 0, stream>>>(sel, topw, meta, list, wgt);
    cvt_bf16_kernel<<<(Tt * Dd / 4) / 256, 256, 0, stream>>>(x, xb, Tt * Dd / 4);
    // w1 [e][D][F] -> w1T [e][F][D]
    transpose_bf16_kernel<<<dim3(Ff/64, Dd/64, Ee), 256, 0, stream>>>(w1, wT, Dd, Ff);
    gemm_g<128, 0, Ff, Dd><<<dim3(Ff/128, 32, 16), 256, 0, stream>>>(xb, wT, h1, meta, list, wgt);
    // w2 [e][F][D] -> w2T [e][D][F] (overwrites w1T after up-proj done)
    transpose_bf16_kernel<<<dim3(Dd/64, Ff/64, Ee), 256, 0, stream>>>(w2, wT, Ff, Dd);
    gemm_g<64, 1, Dd, Ff><<<dim3(Dd/128, 64, 8), 256, 0, stream>>>(h1, wT, out, meta, list, wgt);
    gemm_g<64, 2, Dd, Ff><<<dim3(Dd/128, 64, 8), 256, 0, stream>>>(h1, wT, out, meta, list, wgt);
  } else {
    // dense fallback (round-1 path)
    float* combine = (float*)d_ws;
    float* h1d     = combine + (size_t)Tt * Ee;
    router_kernel<<<Tt, 64, 0, stream>>>(x, gw, logits, combine, nullptr, nullptr, nullptr, 0);
    size_t cb = (size_t)Tt * Ee * sizeof(float);
    size_t avail = ws_size > cb ? (ws_size - cb) : 0;
    long maxrows = (long)(avail / ((size_t)Ff * sizeof(float)));
    int chunk = (maxrows >= Tt) ? Tt : (int)((maxrows / 128) * 128);
    if (chunk < 128) chunk = 128;
    for (int c0 = 0; c0 < Tt; c0 += chunk) {
      int rows = (Tt - c0) < chunk ? (Tt - c0) : chunk;
      for (int e = 0; e < Ee; ++e) {
        gemm_dense<0, Ff, Dd><<<dim3(Ff/128, rows/128), 256, 0, stream>>>(
            x + (size_t)c0 * Dd, w1 + (size_t)e * Dd * Ff, h1d, nullptr, e, 0);
        gemm_dense<1, Dd, Ff><<<dim3(Dd/128, rows/128), 256, 0, stream>>>(
            h1d, w2 + (size_t)e * Ff * Dd, out + (size_t)c0 * Dd,
            combine + (size_t)c0 * Ee, e, (e == 0) ? 1 : 0);
      }
    }
  }
}

// Round 3
// 289.426 us; speedup vs baseline: 3.6255x; 1.3500x over previous
//
#include <hip/hip_runtime.h>
#include <hip/hip_bf16.h>
#include <math.h>

#define Tt 4096
#define Dd 1024
#define Ff 2048
#define Ee 8

typedef unsigned short u16;
typedef short bf16x8 __attribute__((ext_vector_type(8)));
typedef float f32x4 __attribute__((ext_vector_type(4)));

__device__ __forceinline__ u16 f2bf(float f) {
  union { float f; unsigned u; } v; v.f = f;
  unsigned r = v.u + 0x7fffu + ((v.u >> 16) & 1u);
  return (u16)(r >> 16);
}

// async global->LDS, 16B per lane; LDS dest = wave-uniform base + lane*16
__device__ __forceinline__ void gload16(const void* g, void* l) {
  __builtin_amdgcn_global_load_lds(
      (const __attribute__((address_space(1))) unsigned int*)g,
      (__attribute__((address_space(3))) unsigned int*)l, 16, 0, 0);
}

// ---------------- Router: logits only. 4 tokens/block ----------------
__global__ __launch_bounds__(256) void router_kernel(
    const float* __restrict__ x, const float* __restrict__ gw,
    float* __restrict__ logits)
{
  int t = blockIdx.x * 4 + (threadIdx.x >> 6);
  int lane = threadIdx.x & 63;
  const float* xr = x + (size_t)t * Dd;
  float xv[16];
#pragma unroll
  for (int i = 0; i < 4; ++i) {
    float4 v = *reinterpret_cast<const float4*>(xr + lane * 16 + i * 4);
    xv[i*4+0] = v.x; xv[i*4+1] = v.y; xv[i*4+2] = v.z; xv[i*4+3] = v.w;
  }
#pragma unroll
  for (int e = 0; e < Ee; ++e) {
    const float* gr = gw + (size_t)e * Dd + lane * 16;
    float s = 0.f;
#pragma unroll
    for (int i = 0; i < 4; ++i) {
      float4 g = *reinterpret_cast<const float4*>(gr + i * 4);
      s += xv[i*4+0]*g.x + xv[i*4+1]*g.y + xv[i*4+2]*g.z + xv[i*4+3]*g.w;
    }
#pragma unroll
    for (int o = 32; o > 0; o >>= 1) s += __shfl_xor(s, o);
    if (lane == 0) logits[(size_t)t * Ee + e] = s;
  }
}

// ---------------- build: single block, ballot-aggregated histogram ----------------
// meta[0..15]=counts, meta[32..47]=offsets; list/wgt = slot->token/weight
__global__ __launch_bounds__(256) void build_kernel(
    const float* __restrict__ logits, int* __restrict__ meta,
    int* __restrict__ list, float* __restrict__ wgt)
{
  __shared__ int hist[16], cur[16];
  const int tid = threadIdx.x;
  const int lane = tid & 63;
  if (tid < 16) hist[tid] = 0;
  __syncthreads();
  // phase 1: counts
  for (int it = 0; it < Tt / 256; ++it) {
    int t = it * 256 + tid;
    float4 lo = *reinterpret_cast<const float4*>(logits + (size_t)t * 8);
    float4 hi = *reinterpret_cast<const float4*>(logits + (size_t)t * 8 + 4);
    float s[8] = {lo.x, lo.y, lo.z, lo.w, hi.x, hi.y, hi.z, hi.w};
    int i1 = 0; float m1 = s[0];
#pragma unroll
    for (int e = 1; e < 8; ++e) if (s[e] > m1) { m1 = s[e]; i1 = e; }
    int i2 = -1; float m2 = -__builtin_inff();
#pragma unroll
    for (int e = 0; e < 8; ++e) if (e != i1 && s[e] > m2) { m2 = s[e]; i2 = e; }
#pragma unroll
    for (int k = 0; k < 2; ++k) {
      int gg = k ? (8 + i2) : i1;
      unsigned long long m = ~0ull;
#pragma unroll
      for (int b = 0; b < 4; ++b) {
        unsigned long long vb = __ballot((gg >> b) & 1);
        m &= ((gg >> b) & 1) ? vb : ~vb;
      }
      int rank = __popcll(m & ((1ull << lane) - 1));
      if (rank == 0) atomicAdd(&hist[gg], __popcll(m));
    }
  }
  __syncthreads();
  if (tid == 0) {
    int sacc = 0;
    for (int g = 0; g < 16; ++g) {
      meta[g] = hist[g];
      meta[32 + g] = sacc;
      cur[g] = sacc;
      sacc += hist[g];
    }
  }
  __syncthreads();
  // phase 2: assign slots
  for (int it = 0; it < Tt / 256; ++it) {
    int t = it * 256 + tid;
    float4 lo = *reinterpret_cast<const float4*>(logits + (size_t)t * 8);
    float4 hi = *reinterpret_cast<const float4*>(logits + (size_t)t * 8 + 4);
    float s[8] = {lo.x, lo.y, lo.z, lo.w, hi.x, hi.y, hi.z, hi.w};
    int i1 = 0; float m1 = s[0];
#pragma unroll
    for (int e = 1; e < 8; ++e) if (s[e] > m1) { m1 = s[e]; i1 = e; }
    int i2 = -1; float m2 = -__builtin_inff();
#pragma unroll
    for (int e = 0; e < 8; ++e) if (e != i1 && s[e] > m2) { m2 = s[e]; i2 = e; }
    float wa = 1.f / (1.f + expf(m2 - m1));   // renormalized top-2 softmax
#pragma unroll
    for (int k = 0; k < 2; ++k) {
      int gg = k ? (8 + i2) : i1;
      float w = k ? (1.f - wa) : wa;
      unsigned long long m = ~0ull;
#pragma unroll
      for (int b = 0; b < 4; ++b) {
        unsigned long long vb = __ballot((gg >> b) & 1);
        m &= ((gg >> b) & 1) ? vb : ~vb;
      }
      int rank = __popcll(m & ((1ull << lane) - 1));
      int ldr = __ffsll(m) - 1;
      int base = 0;
      if (rank == 0) base = atomicAdd(&cur[gg], __popcll(m));
      base = __shfl(base, ldr);
      list[base + rank] = t;
      wgt[base + rank] = w;
    }
  }
}

// ---------------- conversions ----------------
__global__ __launch_bounds__(256) void cvt_bf16_kernel(
    const float* __restrict__ in, u16* __restrict__ out, int n4)
{
  int i = blockIdx.x * 256 + threadIdx.x;
  if (i >= n4) return;
  float4 v = reinterpret_cast<const float4*>(in)[i];
  ushort4 b;
  b.x = f2bf(v.x); b.y = f2bf(v.y); b.z = f2bf(v.z); b.w = f2bf(v.w);
  reinterpret_cast<ushort4*>(out)[i] = b;
}

// transpose [R][C] f32 -> [C][R] bf16, per expert (blockIdx.z)
__global__ __launch_bounds__(256) void transpose_bf16_kernel(
    const float* __restrict__ in, u16* __restrict__ out, int R, int C)
{
  __shared__ u16 st[64][65];
  const size_t eoff = (size_t)blockIdx.z * R * C;
  const float* ip = in + eoff;
  u16* op = out + eoff;
  int r0 = blockIdx.y * 64, c0 = blockIdx.x * 64;
  int t = threadIdx.x;
  int rr = t >> 2;
  int cb = (t & 3) * 16;
#pragma unroll
  for (int i = 0; i < 4; ++i) {
    float4 v = *reinterpret_cast<const float4*>(ip + (size_t)(r0 + rr) * C + c0 + cb + i * 4);
    st[rr][cb + i*4 + 0] = f2bf(v.x);
    st[rr][cb + i*4 + 1] = f2bf(v.y);
    st[rr][cb + i*4 + 2] = f2bf(v.z);
    st[rr][cb + i*4 + 3] = f2bf(v.w);
  }
  __syncthreads();
#pragma unroll
  for (int i = 0; i < 4; ++i) {
    ushort4 b;
    b.x = st[cb + i*4 + 0][rr];
    b.y = st[cb + i*4 + 1][rr];
    b.z = st[cb + i*4 + 2][rr];
    b.w = st[cb + i*4 + 3][rr];
    *reinterpret_cast<ushort4*>(op + (size_t)(c0 + rr) * R + r0 + cb + i * 4) = b;
  }
}

// ---------------- grouped GEMM, global_load_lds staging (m97 structure) ----------------
// MODE 0: h1[slot] = silu(xb[list[slot]] @ w1T[e]^T)            BM=128
// MODE 1: out[list[slot]]  = wgt[slot] * (h1[slot] @ w2T[e]^T)  groups 0-7,  BM=64
// MODE 2: out[list[slot]] += wgt[slot] * (h1[slot] @ w2T[e]^T)  groups 8-15, BM=64
// Bbase layout: [e][n][k] bf16 (k contiguous).
template<int BM, int MODE, int N_, int K_>
__global__ __launch_bounds__(256) void gemm_g(
    const u16* __restrict__ Abase, const u16* __restrict__ Bbase,
    void* __restrict__ Cout, const int* __restrict__ meta,
    const int* __restrict__ list, const float* __restrict__ wgt)
{
  constexpr int BN  = 128;
  constexpr int WGR = BM / 64;       // wave grid rows
  constexpr int WGC = 4 / WGR;       // wave grid cols
  constexpr int WN  = BN / WGC;      // per-wave N
  constexpr int NFR = WN / 16;       // B frags
  constexpr int CA  = BM / 64;       // A 1KB-chunks per wave

  __shared__ u16 Al[BM * 32];        // linear, 64B rows (glds requires no padding)
  __shared__ u16 Bl[BN * 32];

  const int g   = blockIdx.z + ((MODE == 2) ? 8 : 0);
  const int e   = g & 7;
  const int cnt = meta[g];
  const int rb  = blockIdx.y;
  if (rb * BM >= cnt) return;
  const int off = meta[32 + g];

  const int tid  = threadIdx.x;
  const int lane = tid & 63;
  const int wave = tid >> 6;
  const int wr   = (WGR == 2) ? (wave >> 1) : 0;
  const int wc   = (WGR == 2) ? (wave & 1) : wave;
  const int n0   = blockIdx.x * BN;

  // staging sources: chunk = 16 LDS rows = 1KB; lane l -> row l>>2, 16B piece l&3
  const int l4 = lane >> 2;
  const int kc = (lane & 3) * 8;     // shorts

  const u16* aptr[CA];
  u16* alds[CA];
#pragma unroll
  for (int c = 0; c < CA; ++c) {
    int chunk = wave * CA + c;
    int row = chunk * 16 + l4;
    int i = rb * BM + row;
    if (i >= cnt) i = cnt - 1;       // clamp tail (dup rows, epilogue guards)
    int srow = (MODE == 0) ? list[off + i] : (off + i);
    aptr[c] = Abase + (size_t)srow * K_ + kc;
    alds[c] = Al + chunk * 512;
  }
  const u16* bptr[2];
  u16* blds[2];
#pragma unroll
  for (int c = 0; c < 2; ++c) {
    int chunk = wave * 2 + c;
    int row = chunk * 16 + l4;
    bptr[c] = Bbase + ((size_t)e * N_ + n0 + row) * K_ + kc;
    blds[c] = Bl + chunk * 512;
  }

  f32x4 acc[4][NFR] = {};
  const int r16 = lane & 15;
  const int kq  = (lane >> 4) * 8;

  for (int k0 = 0; k0 < K_; k0 += 32) {
#pragma unroll
    for (int c = 0; c < CA; ++c) gload16(aptr[c] + k0, alds[c]);
#pragma unroll
    for (int c = 0; c < 2; ++c) gload16(bptr[c] + k0, blds[c]);
    __syncthreads();                 // drains vmcnt -> tiles visible

    bf16x8 af[4], bfv[NFR];
#pragma unroll
    for (int m = 0; m < 4; ++m)
      af[m] = *reinterpret_cast<const bf16x8*>(&Al[(wr*64 + m*16 + r16) * 32 + kq]);
#pragma unroll
    for (int n = 0; n < NFR; ++n)
      bfv[n] = *reinterpret_cast<const bf16x8*>(&Bl[(wc*WN + n*16 + r16) * 32 + kq]);
#pragma unroll
    for (int m = 0; m < 4; ++m)
#pragma unroll
      for (int n = 0; n < NFR; ++n)
        acc[m][n] = __builtin_amdgcn_mfma_f32_16x16x32_bf16(af[m], bfv[n], acc[m][n], 0, 0, 0);
    __syncthreads();
  }

  // epilogue: C/D frag layout col=lane&15, row=(lane>>4)*4+reg
  const int colb = n0 + wc * WN + r16;
  const int rb4  = wr * 64 + ((lane >> 4) << 2);
#pragma unroll
  for (int m = 0; m < 4; ++m) {
#pragma unroll
    for (int r = 0; r < 4; ++r) {
      int i = rb * BM + rb4 + m * 16 + r;
      if (i >= cnt) continue;
      if (MODE == 0) {
        u16* hp = (u16*)Cout + (size_t)(off + i) * N_;
#pragma unroll
        for (int n = 0; n < NFR; ++n) {
          float v = acc[m][n][r];
          v = v / (1.f + expf(-v));            // silu
          hp[colb + n * 16] = f2bf(v);
        }
      } else {
        int   tok = list[off + i];
        float w   = wgt[off + i];
        float* o = (float*)Cout + (size_t)tok * N_;
#pragma unroll
        for (int n = 0; n < NFR; ++n) {
          float v = w * acc[m][n][r];
          if (MODE == 1) o[colb + n * 16] = v;
          else           o[colb + n * 16] += v;
        }
      }
    }
  }
}

// ---------------- dense fallback (small-ws path) ----------------
__global__ __launch_bounds__(256) void combine_kernel(
    const float* __restrict__ logits, float* __restrict__ combine)
{
  int t = blockIdx.x * 256 + threadIdx.x;
  if (t >= Tt) return;
  float4 lo = *reinterpret_cast<const float4*>(logits + (size_t)t * 8);
  float4 hi = *reinterpret_cast<const float4*>(logits + (size_t)t * 8 + 4);
  float s[8] = {lo.x, lo.y, lo.z, lo.w, hi.x, hi.y, hi.z, hi.w};
  int i1 = 0; float m1 = s[0];
#pragma unroll
  for (int e = 1; e < 8; ++e) if (s[e] > m1) { m1 = s[e]; i1 = e; }
  int i2 = -1; float m2 = -__builtin_inff();
#pragma unroll
  for (int e = 0; e < 8; ++e) if (e != i1 && s[e] > m2) { m2 = s[e]; i2 = e; }
  float wa = 1.f / (1.f + expf(m2 - m1));
#pragma unroll
  for (int e = 0; e < 8; ++e)
    combine[(size_t)t * 8 + e] = (e == i1) ? wa : ((e == i2) ? (1.f - wa) : 0.f);
}

template<int MODE, int N_, int K_>
__global__ __launch_bounds__(256) void gemm_dense(
    const float* __restrict__ A, const float* __restrict__ Bg,
    float* __restrict__ C, const float* __restrict__ combine,
    int expert, int first)
{
  constexpr int BM = 128, BN = 128, BK = 32, LDT = 40;
  __shared__ u16 Al[BM * LDT];
  __shared__ u16 Bl[BN * LDT];
  const int tid  = threadIdx.x;
  const int lane = tid & 63;
  const int wave = tid >> 6;
  const int wr = wave >> 1, wc = wave & 1;
  const int m0 = blockIdx.y * BM;
  const int n0 = blockIdx.x * BN;
  f32x4 acc[4][4] = {};
  for (int k0 = 0; k0 < K_; k0 += BK) {
#pragma unroll
    for (int i = 0; i < 4; ++i) {
      int f = tid + 256 * i;
      int row = f >> 3;
      int c4 = (f & 7) << 2;
      float4 v = *reinterpret_cast<const float4*>(A + (size_t)(m0 + row) * K_ + k0 + c4);
      ushort4 b;
      b.x = f2bf(v.x); b.y = f2bf(v.y); b.z = f2bf(v.z); b.w = f2bf(v.w);
      *reinterpret_cast<ushort4*>(&Al[row * LDT + c4]) = b;
    }
    {
      int n  = tid & 127;
      int kb = (tid >> 7) << 4;
      const float* bp = Bg + (size_t)(k0 + kb) * N_ + n0 + n;
      u16 tmp[16];
#pragma unroll
      for (int kk = 0; kk < 16; ++kk)
        tmp[kk] = f2bf(bp[(size_t)kk * N_]);
      u16* p = &Bl[n * LDT + kb];
#pragma unroll
      for (int i = 0; i < 4; ++i) {
        ushort4 b;
        b.x = tmp[i*4+0]; b.y = tmp[i*4+1]; b.z = tmp[i*4+2]; b.w = tmp[i*4+3];
        *reinterpret_cast<ushort4*>(p + i * 4) = b;
      }
    }
    __syncthreads();
    bf16x8 af[4], bfr[4];
    const int kq  = (lane >> 4) << 3;
    const int r16 = lane & 15;
#pragma unroll
    for (int m = 0; m < 4; ++m)
      af[m] = *reinterpret_cast<const bf16x8*>(&Al[(wr*64 + m*16 + r16) * LDT + kq]);
#pragma unroll
    for (int n = 0; n < 4; ++n)
      bfr[n] = *reinterpret_cast<const bf16x8*>(&Bl[(wc*64 + n*16 + r16) * LDT + kq]);
#pragma unroll
    for (int m = 0; m < 4; ++m)
#pragma unroll
      for (int n = 0; n < 4; ++n)
        acc[m][n] = __builtin_amdgcn_mfma_f32_16x16x32_bf16(af[m], bfr[n], acc[m][n], 0, 0, 0);
    __syncthreads();
  }
  const int col0 = n0 + wc * 64 + (lane & 15);
  const int rbs  = m0 + wr * 64 + ((lane >> 4) << 2);
#pragma unroll
  for (int m = 0; m < 4; ++m) {
#pragma unroll
    for (int r = 0; r < 4; ++r) {
      int row = rbs + m * 16 + r;
      if (MODE == 0) {
#pragma unroll
        for (int n = 0; n < 4; ++n) {
          float v = acc[m][n][r];
          v = v / (1.f + expf(-v));
          C[(size_t)row * N_ + col0 + n * 16] = v;
        }
      } else {
        float w = combine[(size_t)row * Ee + expert];
        if (first) {
#pragma unroll
          for (int n = 0; n < 4; ++n)
            C[(size_t)row * N_ + col0 + n * 16] = w * acc[m][n][r];
        } else {
#pragma unroll
          for (int n = 0; n < 4; ++n)
            C[(size_t)row * N_ + col0 + n * 16] += w * acc[m][n][r];
        }
      }
    }
  }
}

extern "C" void kernel_launch(void* const* d_in, const int* in_sizes, int n_in,
                              void* d_out, int out_size, void* d_ws, size_t ws_size,
                              hipStream_t stream)
{
  const float* x  = (const float*)d_in[0];   // [2,2048,1024]
  const float* gw = (const float*)d_in[1];   // [8,1024]
  const float* w1 = (const float*)d_in[2];   // [8,1024,2048]
  const float* w2 = (const float*)d_in[3];   // [8,2048,1024]
  float* out    = (float*)d_out;
  float* logits = out + (size_t)Tt * Dd;

  int*   meta = (int*)d_ws;                       // 64 ints
  int*   list = (int*)((char*)d_ws + 256);        // 8192 ints
  float* wgt  = (float*)((char*)d_ws + 256 + 32768);
  u16*   xb   = (u16*)((char*)d_ws + 262144);                         // 8 MB
  u16*   h1   = (u16*)((char*)d_ws + 262144 + 8388608);               // 32 MB
  u16*   wT   = (u16*)((char*)d_ws + 262144 + 8388608 + 33554432);    // 33.5 MB
  const size_t NEED = 262144ull + 8388608ull + 33554432ull + 33554432ull;

  router_kernel<<<Tt / 4, 256, 0, stream>>>(x, gw, logits);

  if (ws_size >= NEED) {
    build_kernel<<<1, 256, 0, stream>>>(logits, meta, list, wgt);
    cvt_bf16_kernel<<<(Tt * Dd / 4) / 256, 256, 0, stream>>>(x, xb, Tt * Dd / 4);
    transpose_bf16_kernel<<<dim3(Ff/64, Dd/64, Ee), 256, 0, stream>>>(w1, wT, Dd, Ff);
    gemm_g<128, 0, Ff, Dd><<<dim3(Ff/128, 32, 16), 256, 0, stream>>>(xb, wT, h1, meta, list, wgt);
    transpose_bf16_kernel<<<dim3(Dd/64, Ff/64, Ee), 256, 0, stream>>>(w2, wT, Ff, Dd);
    gemm_g<64, 1, Dd, Ff><<<dim3(Dd/128, 64, 8), 256, 0, stream>>>(h1, wT, out, meta, list, wgt);
    gemm_g<64, 2, Dd, Ff><<<dim3(Dd/128, 64, 8), 256, 0, stream>>>(h1, wT, out, meta, list, wgt);
  } else {
    float* combine = (float*)d_ws;
    float* h1d     = combine + (size_t)Tt * Ee;
    combine_kernel<<<Tt / 256, 256, 0, stream>>>(logits, combine);
    size_t cb = (size_t)Tt * Ee * sizeof(float);
    size_t avail = ws_size > cb ? (ws_size - cb) : 0;
    long maxrows = (long)(avail / ((size_t)Ff * sizeof(float)));
    int chunk = (maxrows >= Tt) ? Tt : (int)((maxrows / 128) * 128);
    if (chunk < 128) chunk = 128;
    for (int c0 = 0; c0 < Tt; c0 += chunk) {
      int rows = (Tt - c0) < chunk ? (Tt - c0) : chunk;
      for (int e = 0; e < Ee; ++e) {
        gemm_dense<0, Ff, Dd><<<dim3(Ff/128, rows/128), 256, 0, stream>>>(
            x + (size_t)c0 * Dd, w1 + (size_t)e * Dd * Ff, h1d, nullptr, e, 0);
        gemm_dense<1, Dd, Ff><<<dim3(Dd/128, rows/128), 256, 0, stream>>>(
            h1d, w2 + (size_t)e * Ff * Dd, out + (size_t)c0 * Dd,
            combine + (size_t)c0 * Ee, e, (e == 0) ? 1 : 0);
      }
    }
  }
}

// Round 4
// 235.790 us; speedup vs baseline: 4.4502x; 1.2275x over previous
//
#include <hip/hip_runtime.h>
#include <hip/hip_bf16.h>
#include <math.h>

#define Tt 4096
#define Dd 1024
#define Ff 2048
#define Ee 8

typedef unsigned short u16;
typedef short bf16x8 __attribute__((ext_vector_type(8)));
typedef float f32x4 __attribute__((ext_vector_type(4)));

__device__ __forceinline__ u16 f2bf(float f) {
  union { float f; unsigned u; } v; v.f = f;
  unsigned r = v.u + 0x7fffu + ((v.u >> 16) & 1u);
  return (u16)(r >> 16);
}

// async global->LDS, 16B per lane; LDS dest = wave-uniform base + lane*16
__device__ __forceinline__ void gload16(const void* g, void* l) {
  __builtin_amdgcn_global_load_lds(
      (const __attribute__((address_space(1))) unsigned int*)g,
      (__attribute__((address_space(3))) unsigned int*)l, 16, 0, 0);
}

// ---------------- Router: logits only. 4 tokens/block ----------------
__global__ __launch_bounds__(256) void router_kernel(
    const float* __restrict__ x, const float* __restrict__ gw,
    float* __restrict__ logits)
{
  int t = blockIdx.x * 4 + (threadIdx.x >> 6);
  int lane = threadIdx.x & 63;
  const float* xr = x + (size_t)t * Dd;
  float xv[16];
#pragma unroll
  for (int i = 0; i < 4; ++i) {
    float4 v = *reinterpret_cast<const float4*>(xr + lane * 16 + i * 4);
    xv[i*4+0] = v.x; xv[i*4+1] = v.y; xv[i*4+2] = v.z; xv[i*4+3] = v.w;
  }
#pragma unroll
  for (int e = 0; e < Ee; ++e) {
    const float* gr = gw + (size_t)e * Dd + lane * 16;
    float s = 0.f;
#pragma unroll
    for (int i = 0; i < 4; ++i) {
      float4 g = *reinterpret_cast<const float4*>(gr + i * 4);
      s += xv[i*4+0]*g.x + xv[i*4+1]*g.y + xv[i*4+2]*g.z + xv[i*4+3]*g.w;
    }
#pragma unroll
    for (int o = 32; o > 0; o >>= 1) s += __shfl_xor(s, o);
    if (lane == 0) logits[(size_t)t * Ee + e] = s;
  }
}

// ---------------- build: single block, ballot-aggregated histogram ----------------
// meta[0..15]=counts, meta[32..47]=offsets; list/wgt = slot->token/weight
__global__ __launch_bounds__(256) void build_kernel(
    const float* __restrict__ logits, int* __restrict__ meta,
    int* __restrict__ list, float* __restrict__ wgt)
{
  __shared__ int hist[16], cur[16];
  const int tid = threadIdx.x;
  const int lane = tid & 63;
  if (tid < 16) hist[tid] = 0;
  __syncthreads();
  for (int it = 0; it < Tt / 256; ++it) {
    int t = it * 256 + tid;
    float4 lo = *reinterpret_cast<const float4*>(logits + (size_t)t * 8);
    float4 hi = *reinterpret_cast<const float4*>(logits + (size_t)t * 8 + 4);
    float s[8] = {lo.x, lo.y, lo.z, lo.w, hi.x, hi.y, hi.z, hi.w};
    int i1 = 0; float m1 = s[0];
#pragma unroll
    for (int e = 1; e < 8; ++e) if (s[e] > m1) { m1 = s[e]; i1 = e; }
    int i2 = -1; float m2 = -__builtin_inff();
#pragma unroll
    for (int e = 0; e < 8; ++e) if (e != i1 && s[e] > m2) { m2 = s[e]; i2 = e; }
#pragma unroll
    for (int k = 0; k < 2; ++k) {
      int gg = k ? (8 + i2) : i1;
      unsigned long long m = ~0ull;
#pragma unroll
      for (int b = 0; b < 4; ++b) {
        unsigned long long vb = __ballot((gg >> b) & 1);
        m &= ((gg >> b) & 1) ? vb : ~vb;
      }
      int rank = __popcll(m & ((1ull << lane) - 1));
      if (rank == 0) atomicAdd(&hist[gg], __popcll(m));
    }
  }
  __syncthreads();
  if (tid == 0) {
    int sacc = 0;
    for (int g = 0; g < 16; ++g) {
      meta[g] = hist[g];
      meta[32 + g] = sacc;
      cur[g] = sacc;
      sacc += hist[g];
    }
  }
  __syncthreads();
  for (int it = 0; it < Tt / 256; ++it) {
    int t = it * 256 + tid;
    float4 lo = *reinterpret_cast<const float4*>(logits + (size_t)t * 8);
    float4 hi = *reinterpret_cast<const float4*>(logits + (size_t)t * 8 + 4);
    float s[8] = {lo.x, lo.y, lo.z, lo.w, hi.x, hi.y, hi.z, hi.w};
    int i1 = 0; float m1 = s[0];
#pragma unroll
    for (int e = 1; e < 8; ++e) if (s[e] > m1) { m1 = s[e]; i1 = e; }
    int i2 = -1; float m2 = -__builtin_inff();
#pragma unroll
    for (int e = 0; e < 8; ++e) if (e != i1 && s[e] > m2) { m2 = s[e]; i2 = e; }
    float wa = 1.f / (1.f + expf(m2 - m1));   // renormalized top-2 softmax
#pragma unroll
    for (int k = 0; k < 2; ++k) {
      int gg = k ? (8 + i2) : i1;
      float w = k ? (1.f - wa) : wa;
      unsigned long long m = ~0ull;
#pragma unroll
      for (int b = 0; b < 4; ++b) {
        unsigned long long vb = __ballot((gg >> b) & 1);
        m &= ((gg >> b) & 1) ? vb : ~vb;
      }
      int rank = __popcll(m & ((1ull << lane) - 1));
      int ldr = __ffsll(m) - 1;
      int base = 0;
      if (rank == 0) base = atomicAdd(&cur[gg], __popcll(m));
      base = __shfl(base, ldr);
      list[base + rank] = t;
      wgt[base + rank] = w;
    }
  }
}

// ---------------- conversions ----------------
__global__ __launch_bounds__(256) void cvt_bf16_kernel(
    const float* __restrict__ in, u16* __restrict__ out, int n4)
{
  int i = blockIdx.x * 256 + threadIdx.x;
  if (i >= n4) return;
  float4 v = reinterpret_cast<const float4*>(in)[i];
  ushort4 b;
  b.x = f2bf(v.x); b.y = f2bf(v.y); b.z = f2bf(v.z); b.w = f2bf(v.w);
  reinterpret_cast<ushort4*>(out)[i] = b;
}

// transpose [R][C] f32 -> [C][R] bf16, per expert (blockIdx.z)
__global__ __launch_bounds__(256) void transpose_bf16_kernel(
    const float* __restrict__ in, u16* __restrict__ out, int R, int C)
{
  __shared__ u16 st[64][65];
  const size_t eoff = (size_t)blockIdx.z * R * C;
  const float* ip = in + eoff;
  u16* op = out + eoff;
  int r0 = blockIdx.y * 64, c0 = blockIdx.x * 64;
  int t = threadIdx.x;
  int rr = t >> 2;
  int cb = (t & 3) * 16;
#pragma unroll
  for (int i = 0; i < 4; ++i) {
    float4 v = *reinterpret_cast<const float4*>(ip + (size_t)(r0 + rr) * C + c0 + cb + i * 4);
    st[rr][cb + i*4 + 0] = f2bf(v.x);
    st[rr][cb + i*4 + 1] = f2bf(v.y);
    st[rr][cb + i*4 + 2] = f2bf(v.z);
    st[rr][cb + i*4 + 3] = f2bf(v.w);
  }
  __syncthreads();
#pragma unroll
  for (int i = 0; i < 4; ++i) {
    ushort4 b;
    b.x = st[cb + i*4 + 0][rr];
    b.y = st[cb + i*4 + 1][rr];
    b.z = st[cb + i*4 + 2][rr];
    b.w = st[cb + i*4 + 3][rr];
    *reinterpret_cast<ushort4*>(op + (size_t)(c0 + rr) * R + r0 + cb + i * 4) = b;
  }
}

// ---------------- grouped GEMM, glds staging, double-buffered K-loop ----------------
// MODE 0: h1[slot] = silu(xb[list[slot]] @ w1T[e]^T)             BM=128, z=16 groups
// MODE 1: out[list[slot]] += wgt[slot]*(h1[slot] @ w2T[e]^T)     BM=64,  z=16 groups (atomicAdd)
// Bbase layout: [e][n][k] bf16 (k contiguous).
template<int BM, int MODE, int N_, int K_>
__global__ __launch_bounds__(256) void gemm_g(
    const u16* __restrict__ Abase, const u16* __restrict__ Bbase,
    void* __restrict__ Cout, const int* __restrict__ meta,
    const int* __restrict__ list, const float* __restrict__ wgt)
{
  constexpr int BN  = 128;
  constexpr int WGR = BM / 64;       // wave grid rows
  constexpr int WGC = 4 / WGR;       // wave grid cols
  constexpr int WN  = BN / WGC;      // per-wave N
  constexpr int NFR = WN / 16;       // B frags
  constexpr int CA  = BM / 64;       // A 1KB-chunks per wave
  constexpr int ABUF = BM * 32;      // u16 per A buffer
  constexpr int BBUF = BN * 32;

  __shared__ u16 Al[2 * ABUF];       // linear 64B rows (glds needs contiguous dest)
  __shared__ u16 Bl[2 * BBUF];

  const int g   = blockIdx.z;
  const int e   = g & 7;
  const int cnt = meta[g];
  const int rb  = blockIdx.y;
  if (rb * BM >= cnt) return;
  const int off = meta[32 + g];

  const int tid  = threadIdx.x;
  const int lane = tid & 63;
  const int wave = tid >> 6;
  const int wr   = (WGR == 2) ? (wave >> 1) : 0;
  const int wc   = (WGR == 2) ? (wave & 1) : wave;
  const int n0   = blockIdx.x * BN;

  // staging: chunk = 16 LDS rows = 1KB; lane l -> row l>>2, 16B piece l&3
  const int l4 = lane >> 2;
  const int kc = (lane & 3) * 8;     // shorts

  const u16* aptr[CA];
  u16* alds[CA];
#pragma unroll
  for (int c = 0; c < CA; ++c) {
    int chunk = wave * CA + c;
    int row = chunk * 16 + l4;
    int i = rb * BM + row;
    if (i >= cnt) i = cnt - 1;       // clamp tail (dup rows; epilogue guards)
    int srow = (MODE == 0) ? list[off + i] : (off + i);
    aptr[c] = Abase + (size_t)srow * K_ + kc;
    alds[c] = Al + chunk * 512;
  }
  const u16* bptr[2];
  u16* blds[2];
#pragma unroll
  for (int c = 0; c < 2; ++c) {
    int chunk = wave * 2 + c;
    int row = chunk * 16 + l4;
    bptr[c] = Bbase + ((size_t)e * N_ + n0 + row) * K_ + kc;
    blds[c] = Bl + chunk * 512;
  }

  f32x4 acc[4][NFR] = {};
  const int r16 = lane & 15;
  const int kq  = (lane >> 4) * 8;
  constexpr int NT = K_ / 32;

  // prologue: stage tile 0 into buffer 0
#pragma unroll
  for (int c = 0; c < CA; ++c) gload16(aptr[c], alds[c]);
#pragma unroll
  for (int c = 0; c < 2; ++c) gload16(bptr[c], blds[c]);
  __syncthreads();

  int cur = 0;
  for (int t = 0; t < NT; ++t) {
    // issue next-tile loads into the other buffer (fly under ds_read+MFMA)
    if (t + 1 < NT) {
      int k0 = (t + 1) * 32;
      int nb = cur ^ 1;
#pragma unroll
      for (int c = 0; c < CA; ++c) gload16(aptr[c] + k0, alds[c] + nb * ABUF);
#pragma unroll
      for (int c = 0; c < 2; ++c) gload16(bptr[c] + k0, blds[c] + nb * BBUF);
    }
    const u16* Ab = Al + cur * ABUF;
    const u16* Bb = Bl + cur * BBUF;
    bf16x8 af[4], bfv[NFR];
#pragma unroll
    for (int m = 0; m < 4; ++m)
      af[m] = *reinterpret_cast<const bf16x8*>(&Ab[(wr*64 + m*16 + r16) * 32 + kq]);
#pragma unroll
    for (int n = 0; n < NFR; ++n)
      bfv[n] = *reinterpret_cast<const bf16x8*>(&Bb[(wc*WN + n*16 + r16) * 32 + kq]);
#pragma unroll
    for (int m = 0; m < 4; ++m)
#pragma unroll
      for (int n = 0; n < NFR; ++n)
        acc[m][n] = __builtin_amdgcn_mfma_f32_16x16x32_bf16(af[m], bfv[n], acc[m][n], 0, 0, 0);
    __syncthreads();   // implicit vmcnt(0): next buffer ready; all waves done with cur
    cur ^= 1;
  }

  // epilogue: C/D frag layout col=lane&15, row=(lane>>4)*4+reg
  const int colb = n0 + wc * WN + r16;
  const int rb4  = wr * 64 + ((lane >> 4) << 2);
#pragma unroll
  for (int m = 0; m < 4; ++m) {
#pragma unroll
    for (int r = 0; r < 4; ++r) {
      int i = rb * BM + rb4 + m * 16 + r;
      if (i >= cnt) continue;
      if (MODE == 0) {
        u16* hp = (u16*)Cout + (size_t)(off + i) * N_;
#pragma unroll
        for (int n = 0; n < NFR; ++n) {
          float v = acc[m][n][r];
          v = v / (1.f + expf(-v));            // silu
          hp[colb + n * 16] = f2bf(v);
        }
      } else {
        int   tok = list[off + i];
        float w   = wgt[off + i];
        float* o = (float*)Cout + (size_t)tok * N_;
#pragma unroll
        for (int n = 0; n < NFR; ++n)
          atomicAdd(&o[colb + n * 16], w * acc[m][n][r]);
      }
    }
  }
}

// ---------------- dense fallback (small-ws path) ----------------
__global__ __launch_bounds__(256) void combine_kernel(
    const float* __restrict__ logits, float* __restrict__ combine)
{
  int t = blockIdx.x * 256 + threadIdx.x;
  if (t >= Tt) return;
  float4 lo = *reinterpret_cast<const float4*>(logits + (size_t)t * 8);
  float4 hi = *reinterpret_cast<const float4*>(logits + (size_t)t * 8 + 4);
  float s[8] = {lo.x, lo.y, lo.z, lo.w, hi.x, hi.y, hi.z, hi.w};
  int i1 = 0; float m1 = s[0];
#pragma unroll
  for (int e = 1; e < 8; ++e) if (s[e] > m1) { m1 = s[e]; i1 = e; }
  int i2 = -1; float m2 = -__builtin_inff();
#pragma unroll
  for (int e = 0; e < 8; ++e) if (e != i1 && s[e] > m2) { m2 = s[e]; i2 = e; }
  float wa = 1.f / (1.f + expf(m2 - m1));
#pragma unroll
  for (int e = 0; e < 8; ++e)
    combine[(size_t)t * 8 + e] = (e == i1) ? wa : ((e == i2) ? (1.f - wa) : 0.f);
}

template<int MODE, int N_, int K_>
__global__ __launch_bounds__(256) void gemm_dense(
    const float* __restrict__ A, const float* __restrict__ Bg,
    float* __restrict__ C, const float* __restrict__ combine,
    int expert, int first)
{
  constexpr int BM = 128, BN = 128, BK = 32, LDT = 40;
  __shared__ u16 Al[BM * LDT];
  __shared__ u16 Bl[BN * LDT];
  const int tid  = threadIdx.x;
  const int lane = tid & 63;
  const int wave = tid >> 6;
  const int wr = wave >> 1, wc = wave & 1;
  const int m0 = blockIdx.y * BM;
  const int n0 = blockIdx.x * BN;
  f32x4 acc[4][4] = {};
  for (int k0 = 0; k0 < K_; k0 += BK) {
#pragma unroll
    for (int i = 0; i < 4; ++i) {
      int f = tid + 256 * i;
      int row = f >> 3;
      int c4 = (f & 7) << 2;
      float4 v = *reinterpret_cast<const float4*>(A + (size_t)(m0 + row) * K_ + k0 + c4);
      ushort4 b;
      b.x = f2bf(v.x); b.y = f2bf(v.y); b.z = f2bf(v.z); b.w = f2bf(v.w);
      *reinterpret_cast<ushort4*>(&Al[row * LDT + c4]) = b;
    }
    {
      int n  = tid & 127;
      int kb = (tid >> 7) << 4;
      const float* bp = Bg + (size_t)(k0 + kb) * N_ + n0 + n;
      u16 tmp[16];
#pragma unroll
      for (int kk = 0; kk < 16; ++kk)
        tmp[kk] = f2bf(bp[(size_t)kk * N_]);
      u16* p = &Bl[n * LDT + kb];
#pragma unroll
      for (int i = 0; i < 4; ++i) {
        ushort4 b;
        b.x = tmp[i*4+0]; b.y = tmp[i*4+1]; b.z = tmp[i*4+2]; b.w = tmp[i*4+3];
        *reinterpret_cast<ushort4*>(p + i * 4) = b;
      }
    }
    __syncthreads();
    bf16x8 af[4], bfr[4];
    const int kq  = (lane >> 4) << 3;
    const int r16 = lane & 15;
#pragma unroll
    for (int m = 0; m < 4; ++m)
      af[m] = *reinterpret_cast<const bf16x8*>(&Al[(wr*64 + m*16 + r16) * LDT + kq]);
#pragma unroll
    for (int n = 0; n < 4; ++n)
      bfr[n] = *reinterpret_cast<const bf16x8*>(&Bl[(wc*64 + n*16 + r16) * LDT + kq]);
#pragma unroll
    for (int m = 0; m < 4; ++m)
#pragma unroll
      for (int n = 0; n < 4; ++n)
        acc[m][n] = __builtin_amdgcn_mfma_f32_16x16x32_bf16(af[m], bfr[n], acc[m][n], 0, 0, 0);
    __syncthreads();
  }
  const int col0 = n0 + wc * 64 + (lane & 15);
  const int rbs  = m0 + wr * 64 + ((lane >> 4) << 2);
#pragma unroll
  for (int m = 0; m < 4; ++m) {
#pragma unroll
    for (int r = 0; r < 4; ++r) {
      int row = rbs + m * 16 + r;
      if (MODE == 0) {
#pragma unroll
        for (int n = 0; n < 4; ++n) {
          float v = acc[m][n][r];
          v = v / (1.f + expf(-v));
          C[(size_t)row * N_ + col0 + n * 16] = v;
        }
      } else {
        float w = combine[(size_t)row * Ee + expert];
        if (first) {
#pragma unroll
          for (int n = 0; n < 4; ++n)
            C[(size_t)row * N_ + col0 + n * 16] = w * acc[m][n][r];
        } else {
#pragma unroll
          for (int n = 0; n < 4; ++n)
            C[(size_t)row * N_ + col0 + n * 16] += w * acc[m][n][r];
        }
      }
    }
  }
}

extern "C" void kernel_launch(void* const* d_in, const int* in_sizes, int n_in,
                              void* d_out, int out_size, void* d_ws, size_t ws_size,
                              hipStream_t stream)
{
  const float* x  = (const float*)d_in[0];   // [2,2048,1024]
  const float* gw = (const float*)d_in[1];   // [8,1024]
  const float* w1 = (const float*)d_in[2];   // [8,1024,2048]
  const float* w2 = (const float*)d_in[3];   // [8,2048,1024]
  float* out    = (float*)d_out;
  float* logits = out + (size_t)Tt * Dd;

  int*   meta = (int*)d_ws;                       // 64 ints
  int*   list = (int*)((char*)d_ws + 256);        // 8192 ints
  float* wgt  = (float*)((char*)d_ws + 256 + 32768);
  u16*   xb   = (u16*)((char*)d_ws + 262144);                         // 8 MB
  u16*   h1   = (u16*)((char*)d_ws + 262144 + 8388608);               // 32 MB
  u16*   wT   = (u16*)((char*)d_ws + 262144 + 8388608 + 33554432);    // 33.5 MB
  const size_t NEED = 262144ull + 8388608ull + 33554432ull + 33554432ull;

  router_kernel<<<Tt / 4, 256, 0, stream>>>(x, gw, logits);

  if (ws_size >= NEED) {
    hipMemsetAsync(out, 0, (size_t)Tt * Dd * sizeof(float), stream);
    build_kernel<<<1, 256, 0, stream>>>(logits, meta, list, wgt);
    cvt_bf16_kernel<<<(Tt * Dd / 4) / 256, 256, 0, stream>>>(x, xb, Tt * Dd / 4);
    transpose_bf16_kernel<<<dim3(Ff/64, Dd/64, Ee), 256, 0, stream>>>(w1, wT, Dd, Ff);
    gemm_g<128, 0, Ff, Dd><<<dim3(Ff/128, 32, 16), 256, 0, stream>>>(xb, wT, h1, meta, list, wgt);
    transpose_bf16_kernel<<<dim3(Dd/64, Ff/64, Ee), 256, 0, stream>>>(w2, wT, Ff, Dd);
    gemm_g<64, 1, Dd, Ff><<<dim3(Dd/128, 64, 16), 256, 0, stream>>>(h1, wT, out, meta, list, wgt);
  } else {
    float* combine = (float*)d_ws;
    float* h1d     = combine + (size_t)Tt * Ee;
    combine_kernel<<<Tt / 256, 256, 0, stream>>>(logits, combine);
    size_t cb = (size_t)Tt * Ee * sizeof(float);
    size_t avail = ws_size > cb ? (ws_size - cb) : 0;
    long maxrows = (long)(avail / ((size_t)Ff * sizeof(float)));
    int chunk = (maxrows >= Tt) ? Tt : (int)((maxrows / 128) * 128);
    if (chunk < 128) chunk = 128;
    for (int c0 = 0; c0 < Tt; c0 += chunk) {
      int rows = (Tt - c0) < chunk ? (Tt - c0) : chunk;
      for (int e = 0; e < Ee; ++e) {
        gemm_dense<0, Ff, Dd><<<dim3(Ff/128, rows/128), 256, 0, stream>>>(
            x + (size_t)c0 * Dd, w1 + (size_t)e * Dd * Ff, h1d, nullptr, e, 0);
        gemm_dense<1, Dd, Ff><<<dim3(Dd/128, rows/128), 256, 0, stream>>>(
            h1d, w2 + (size_t)e * Ff * Dd, out + (size_t)c0 * Dd,
            combine + (size_t)c0 * Ee, e, (e == 0) ? 1 : 0);
      }
    }
  }
}

// Round 5
// 217.830 us; speedup vs baseline: 4.8171x; 1.0824x over previous
//
#include <hip/hip_runtime.h>
#include <hip/hip_bf16.h>
#include <math.h>

#define Tt 4096
#define Dd 1024
#define Ff 2048
#define Ee 8

typedef unsigned short u16;
typedef short bf16x8 __attribute__((ext_vector_type(8)));
typedef float f32x4 __attribute__((ext_vector_type(4)));

__device__ __forceinline__ u16 f2bf(float f) {
  union { float f; unsigned u; } v; v.f = f;
  unsigned r = v.u + 0x7fffu + ((v.u >> 16) & 1u);
  return (u16)(r >> 16);
}

// async global->LDS, 16B per lane; LDS dest = wave-uniform base + lane*16
__device__ __forceinline__ void gload16(const void* g, void* l) {
  __builtin_amdgcn_global_load_lds(
      (const __attribute__((address_space(1))) unsigned int*)g,
      (__attribute__((address_space(3))) unsigned int*)l, 16, 0, 0);
}

// ---------------- Router: logits only. 4 tokens/block ----------------
__global__ __launch_bounds__(256) void router_kernel(
    const float* __restrict__ x, const float* __restrict__ gw,
    float* __restrict__ logits)
{
  int t = blockIdx.x * 4 + (threadIdx.x >> 6);
  int lane = threadIdx.x & 63;
  const float* xr = x + (size_t)t * Dd;
  float xv[16];
#pragma unroll
  for (int i = 0; i < 4; ++i) {
    float4 v = *reinterpret_cast<const float4*>(xr + lane * 16 + i * 4);
    xv[i*4+0] = v.x; xv[i*4+1] = v.y; xv[i*4+2] = v.z; xv[i*4+3] = v.w;
  }
#pragma unroll
  for (int e = 0; e < Ee; ++e) {
    const float* gr = gw + (size_t)e * Dd + lane * 16;
    float s = 0.f;
#pragma unroll
    for (int i = 0; i < 4; ++i) {
      float4 g = *reinterpret_cast<const float4*>(gr + i * 4);
      s += xv[i*4+0]*g.x + xv[i*4+1]*g.y + xv[i*4+2]*g.z + xv[i*4+3]*g.w;
    }
#pragma unroll
    for (int o = 32; o > 0; o >>= 1) s += __shfl_xor(s, o);
    if (lane == 0) logits[(size_t)t * Ee + e] = s;
  }
}

// ---------------- build: single block, 8 per-expert groups ----------------
// meta[0..7]=counts, meta[32..39]=offsets; list/wgt = slot->token/weight
__global__ __launch_bounds__(256) void build_kernel(
    const float* __restrict__ logits, int* __restrict__ meta,
    int* __restrict__ list, float* __restrict__ wgt)
{
  __shared__ int hist[8], cur[8];
  const int tid = threadIdx.x;
  const int lane = tid & 63;
  if (tid < 8) hist[tid] = 0;
  __syncthreads();
  for (int it = 0; it < Tt / 256; ++it) {
    int t = it * 256 + tid;
    float4 lo = *reinterpret_cast<const float4*>(logits + (size_t)t * 8);
    float4 hi = *reinterpret_cast<const float4*>(logits + (size_t)t * 8 + 4);
    float s[8] = {lo.x, lo.y, lo.z, lo.w, hi.x, hi.y, hi.z, hi.w};
    int i1 = 0; float m1 = s[0];
#pragma unroll
    for (int e = 1; e < 8; ++e) if (s[e] > m1) { m1 = s[e]; i1 = e; }
    int i2 = -1; float m2 = -__builtin_inff();
#pragma unroll
    for (int e = 0; e < 8; ++e) if (e != i1 && s[e] > m2) { m2 = s[e]; i2 = e; }
#pragma unroll
    for (int k = 0; k < 2; ++k) {
      int gg = k ? i2 : i1;
      unsigned long long m = ~0ull;
#pragma unroll
      for (int b = 0; b < 3; ++b) {
        unsigned long long vb = __ballot((gg >> b) & 1);
        m &= ((gg >> b) & 1) ? vb : ~vb;
      }
      int rank = __popcll(m & ((1ull << lane) - 1));
      if (rank == 0) atomicAdd(&hist[gg], __popcll(m));
    }
  }
  __syncthreads();
  if (tid == 0) {
    int sacc = 0;
    for (int g = 0; g < 8; ++g) {
      meta[g] = hist[g];
      meta[32 + g] = sacc;
      cur[g] = sacc;
      sacc += hist[g];
    }
  }
  __syncthreads();
  for (int it = 0; it < Tt / 256; ++it) {
    int t = it * 256 + tid;
    float4 lo = *reinterpret_cast<const float4*>(logits + (size_t)t * 8);
    float4 hi = *reinterpret_cast<const float4*>(logits + (size_t)t * 8 + 4);
    float s[8] = {lo.x, lo.y, lo.z, lo.w, hi.x, hi.y, hi.z, hi.w};
    int i1 = 0; float m1 = s[0];
#pragma unroll
    for (int e = 1; e < 8; ++e) if (s[e] > m1) { m1 = s[e]; i1 = e; }
    int i2 = -1; float m2 = -__builtin_inff();
#pragma unroll
    for (int e = 0; e < 8; ++e) if (e != i1 && s[e] > m2) { m2 = s[e]; i2 = e; }
    float wa = 1.f / (1.f + expf(m2 - m1));   // renormalized top-2 softmax
#pragma unroll
    for (int k = 0; k < 2; ++k) {
      int gg = k ? i2 : i1;
      float w = k ? (1.f - wa) : wa;
      unsigned long long m = ~0ull;
#pragma unroll
      for (int b = 0; b < 3; ++b) {
        unsigned long long vb = __ballot((gg >> b) & 1);
        m &= ((gg >> b) & 1) ? vb : ~vb;
      }
      int rank = __popcll(m & ((1ull << lane) - 1));
      int ldr = __ffsll(m) - 1;
      int base = 0;
      if (rank == 0) base = atomicAdd(&cur[gg], __popcll(m));
      base = __shfl(base, ldr);
      list[base + rank] = t;
      wgt[base + rank] = w;
    }
  }
}

// ---------------- conversions ----------------
__global__ __launch_bounds__(256) void cvt_bf16_kernel(
    const float* __restrict__ in, u16* __restrict__ out, int n4)
{
  int i = blockIdx.x * 256 + threadIdx.x;
  if (i >= n4) return;
  float4 v = reinterpret_cast<const float4*>(in)[i];
  ushort4 b;
  b.x = f2bf(v.x); b.y = f2bf(v.y); b.z = f2bf(v.z); b.w = f2bf(v.w);
  reinterpret_cast<ushort4*>(out)[i] = b;
}

// transpose [R][C] f32 -> [C][R] bf16, per expert (blockIdx.z)
__global__ __launch_bounds__(256) void transpose_bf16_kernel(
    const float* __restrict__ in, u16* __restrict__ out, int R, int C)
{
  __shared__ u16 st[64][65];
  const size_t eoff = (size_t)blockIdx.z * R * C;
  const float* ip = in + eoff;
  u16* op = out + eoff;
  int r0 = blockIdx.y * 64, c0 = blockIdx.x * 64;
  int t = threadIdx.x;
  int rr = t >> 2;
  int cb = (t & 3) * 16;
#pragma unroll
  for (int i = 0; i < 4; ++i) {
    float4 v = *reinterpret_cast<const float4*>(ip + (size_t)(r0 + rr) * C + c0 + cb + i * 4);
    st[rr][cb + i*4 + 0] = f2bf(v.x);
    st[rr][cb + i*4 + 1] = f2bf(v.y);
    st[rr][cb + i*4 + 2] = f2bf(v.z);
    st[rr][cb + i*4 + 3] = f2bf(v.w);
  }
  __syncthreads();
#pragma unroll
  for (int i = 0; i < 4; ++i) {
    ushort4 b;
    b.x = st[cb + i*4 + 0][rr];
    b.y = st[cb + i*4 + 1][rr];
    b.z = st[cb + i*4 + 2][rr];
    b.w = st[cb + i*4 + 3][rr];
    *reinterpret_cast<ushort4*>(op + (size_t)(c0 + rr) * R + r0 + cb + i * 4) = b;
  }
}

// ---------------- grouped GEMM: BM=128, dbuf glds, XCD-chunked swizzle ----------------
// MODE 0: h1[slot] = silu(xb[list[slot]] @ w1T[e]^T)          grid (N/128, 32, 8)
// MODE 1: out[list[slot]] += wgt[slot]*(h1[slot] @ w2T[e]^T)  grid (N/128, 32, 8), atomicAdd
// Bbase layout: [e][n][k] bf16 (k contiguous). One expert (z-plane) per XCD.
template<int MODE, int N_, int K_>
__global__ __launch_bounds__(256) void gemm_g(
    const u16* __restrict__ Abase, const u16* __restrict__ Bbase,
    void* __restrict__ Cout, const int* __restrict__ meta,
    const int* __restrict__ list, const float* __restrict__ wgt)
{
  constexpr int BM = 128, BN = 128;
  constexpr int NXc = N_ / BN;          // grid.x
  constexpr int NYc = 32;               // grid.y (covers worst-case cnt=4096)
  constexpr int NWG = NXc * NYc * 8;
  constexpr int CPX = NWG / 8;          // == NXc*NYc: one expert per XCD
  constexpr int ABUF = BM * 32, BBUF = BN * 32;

  __shared__ u16 Al[2 * ABUF];          // linear 64B rows (glds needs contiguous dest)
  __shared__ u16 Bl[2 * BBUF];

  // bijective XCD swizzle: HW round-robins orig%8 across XCDs; give each XCD
  // one contiguous logical chunk == one z-plane (one expert's panel in its L2).
  const int orig = blockIdx.x + NXc * (blockIdx.y + NYc * blockIdx.z);
  const int swz  = (orig & 7) * CPX + (orig >> 3);
  const int bz   = swz / (NXc * NYc);
  const int rem  = swz - bz * (NXc * NYc);
  const int by   = rem / NXc;
  const int bx   = rem - by * NXc;

  const int e   = bz;
  const int cnt = meta[e];
  if (by * BM >= cnt) return;
  const int off = meta[32 + e];

  const int tid  = threadIdx.x;
  const int lane = tid & 63;
  const int wave = tid >> 6;
  const int wr   = wave >> 1, wc = wave & 1;
  const int n0   = bx * BN;

  // staging: chunk = 16 LDS rows = 1KB; lane l -> row l>>2, 16B piece l&3
  const int l4 = lane >> 2;
  const int kc = (lane & 3) * 8;        // shorts

  const u16* aptr[2];
  u16* alds[2];
#pragma unroll
  for (int c = 0; c < 2; ++c) {
    int chunk = wave * 2 + c;
    int row = chunk * 16 + l4;
    int i = by * BM + row;
    if (i >= cnt) i = cnt - 1;          // clamp tail (dup rows; epilogue guards)
    int srow = (MODE == 0) ? list[off + i] : (off + i);
    aptr[c] = Abase + (size_t)srow * K_ + kc;
    alds[c] = Al + chunk * 512;
  }
  const u16* bptr[2];
  u16* blds[2];
#pragma unroll
  for (int c = 0; c < 2; ++c) {
    int chunk = wave * 2 + c;
    int row = chunk * 16 + l4;
    bptr[c] = Bbase + ((size_t)e * N_ + n0 + row) * K_ + kc;
    blds[c] = Bl + chunk * 512;
  }

  f32x4 acc[4][4] = {};
  const int r16 = lane & 15;
  const int kq  = (lane >> 4) * 8;
  constexpr int NT = K_ / 32;

  // prologue: stage tile 0 into buffer 0
#pragma unroll
  for (int c = 0; c < 2; ++c) gload16(aptr[c], alds[c]);
#pragma unroll
  for (int c = 0; c < 2; ++c) gload16(bptr[c], blds[c]);
  __syncthreads();

  int cur = 0;
  for (int t = 0; t < NT; ++t) {
    if (t + 1 < NT) {                   // next-tile loads fly under ds_read+MFMA
      int k0 = (t + 1) * 32;
      int nb = cur ^ 1;
#pragma unroll
      for (int c = 0; c < 2; ++c) gload16(aptr[c] + k0, alds[c] + nb * ABUF);
#pragma unroll
      for (int c = 0; c < 2; ++c) gload16(bptr[c] + k0, blds[c] + nb * BBUF);
    }
    const u16* Ab = Al + cur * ABUF;
    const u16* Bb = Bl + cur * BBUF;
    bf16x8 af[4], bfv[4];
#pragma unroll
    for (int m = 0; m < 4; ++m)
      af[m] = *reinterpret_cast<const bf16x8*>(&Ab[(wr*64 + m*16 + r16) * 32 + kq]);
#pragma unroll
    for (int n = 0; n < 4; ++n)
      bfv[n] = *reinterpret_cast<const bf16x8*>(&Bb[(wc*64 + n*16 + r16) * 32 + kq]);
#pragma unroll
    for (int m = 0; m < 4; ++m)
#pragma unroll
      for (int n = 0; n < 4; ++n)
        acc[m][n] = __builtin_amdgcn_mfma_f32_16x16x32_bf16(af[m], bfv[n], acc[m][n], 0, 0, 0);
    __syncthreads();   // implicit vmcnt(0) drain: next buffer ready for all waves
    cur ^= 1;
  }

  // epilogue: C/D frag layout col=lane&15, row=(lane>>4)*4+reg
  const int colb = n0 + wc * 64 + r16;
  const int rb4  = wr * 64 + ((lane >> 4) << 2);
#pragma unroll
  for (int m = 0; m < 4; ++m) {
#pragma unroll
    for (int r = 0; r < 4; ++r) {
      int i = by * BM + rb4 + m * 16 + r;
      if (i >= cnt) continue;
      if (MODE == 0) {
        u16* hp = (u16*)Cout + (size_t)(off + i) * N_;
#pragma unroll
        for (int n = 0; n < 4; ++n) {
          float v = acc[m][n][r];
          v = v / (1.f + expf(-v));            // silu
          hp[colb + n * 16] = f2bf(v);
        }
      } else {
        int   tok = list[off + i];
        float w   = wgt[off + i];
        float* o = (float*)Cout + (size_t)tok * N_;
#pragma unroll
        for (int n = 0; n < 4; ++n)
          atomicAdd(&o[colb + n * 16], w * acc[m][n][r]);
      }
    }
  }
}

// ---------------- dense fallback (small-ws path) ----------------
__global__ __launch_bounds__(256) void combine_kernel(
    const float* __restrict__ logits, float* __restrict__ combine)
{
  int t = blockIdx.x * 256 + threadIdx.x;
  if (t >= Tt) return;
  float4 lo = *reinterpret_cast<const float4*>(logits + (size_t)t * 8);
  float4 hi = *reinterpret_cast<const float4*>(logits + (size_t)t * 8 + 4);
  float s[8] = {lo.x, lo.y, lo.z, lo.w, hi.x, hi.y, hi.z, hi.w};
  int i1 = 0; float m1 = s[0];
#pragma unroll
  for (int e = 1; e < 8; ++e) if (s[e] > m1) { m1 = s[e]; i1 = e; }
  int i2 = -1; float m2 = -__builtin_inff();
#pragma unroll
  for (int e = 0; e < 8; ++e) if (e != i1 && s[e] > m2) { m2 = s[e]; i2 = e; }
  float wa = 1.f / (1.f + expf(m2 - m1));
#pragma unroll
  for (int e = 0; e < 8; ++e)
    combine[(size_t)t * 8 + e] = (e == i1) ? wa : ((e == i2) ? (1.f - wa) : 0.f);
}

template<int MODE, int N_, int K_>
__global__ __launch_bounds__(256) void gemm_dense(
    const float* __restrict__ A, const float* __restrict__ Bg,
    float* __restrict__ C, const float* __restrict__ combine,
    int expert, int first)
{
  constexpr int BM = 128, BN = 128, BK = 32, LDT = 40;
  __shared__ u16 Al[BM * LDT];
  __shared__ u16 Bl[BN * LDT];
  const int tid  = threadIdx.x;
  const int lane = tid & 63;
  const int wave = tid >> 6;
  const int wr = wave >> 1, wc = wave & 1;
  const int m0 = blockIdx.y * BM;
  const int n0 = blockIdx.x * BN;
  f32x4 acc[4][4] = {};
  for (int k0 = 0; k0 < K_; k0 += BK) {
#pragma unroll
    for (int i = 0; i < 4; ++i) {
      int f = tid + 256 * i;
      int row = f >> 3;
      int c4 = (f & 7) << 2;
      float4 v = *reinterpret_cast<const float4*>(A + (size_t)(m0 + row) * K_ + k0 + c4);
      ushort4 b;
      b.x = f2bf(v.x); b.y = f2bf(v.y); b.z = f2bf(v.z); b.w = f2bf(v.w);
      *reinterpret_cast<ushort4*>(&Al[row * LDT + c4]) = b;
    }
    {
      int n  = tid & 127;
      int kb = (tid >> 7) << 4;
      const float* bp = Bg + (size_t)(k0 + kb) * N_ + n0 + n;
      u16 tmp[16];
#pragma unroll
      for (int kk = 0; kk < 16; ++kk)
        tmp[kk] = f2bf(bp[(size_t)kk * N_]);
      u16* p = &Bl[n * LDT + kb];
#pragma unroll
      for (int i = 0; i < 4; ++i) {
        ushort4 b;
        b.x = tmp[i*4+0]; b.y = tmp[i*4+1]; b.z = tmp[i*4+2]; b.w = tmp[i*4+3];
        *reinterpret_cast<ushort4*>(p + i * 4) = b;
      }
    }
    __syncthreads();
    bf16x8 af[4], bfr[4];
    const int kq  = (lane >> 4) << 3;
    const int r16 = lane & 15;
#pragma unroll
    for (int m = 0; m < 4; ++m)
      af[m] = *reinterpret_cast<const bf16x8*>(&Al[(wr*64 + m*16 + r16) * LDT + kq]);
#pragma unroll
    for (int n = 0; n < 4; ++n)
      bfr[n] = *reinterpret_cast<const bf16x8*>(&Bl[(wc*64 + n*16 + r16) * LDT + kq]);
#pragma unroll
    for (int m = 0; m < 4; ++m)
#pragma unroll
      for (int n = 0; n < 4; ++n)
        acc[m][n] = __builtin_amdgcn_mfma_f32_16x16x32_bf16(af[m], bfr[n], acc[m][n], 0, 0, 0);
    __syncthreads();
  }
  const int col0 = n0 + wc * 64 + (lane & 15);
  const int rbs  = m0 + wr * 64 + ((lane >> 4) << 2);
#pragma unroll
  for (int m = 0; m < 4; ++m) {
#pragma unroll
    for (int r = 0; r < 4; ++r) {
      int row = rbs + m * 16 + r;
      if (MODE == 0) {
#pragma unroll
        for (int n = 0; n < 4; ++n) {
          float v = acc[m][n][r];
          v = v / (1.f + expf(-v));
          C[(size_t)row * N_ + col0 + n * 16] = v;
        }
      } else {
        float w = combine[(size_t)row * Ee + expert];
        if (first) {
#pragma unroll
          for (int n = 0; n < 4; ++n)
            C[(size_t)row * N_ + col0 + n * 16] = w * acc[m][n][r];
        } else {
#pragma unroll
          for (int n = 0; n < 4; ++n)
            C[(size_t)row * N_ + col0 + n * 16] += w * acc[m][n][r];
        }
      }
    }
  }
}

extern "C" void kernel_launch(void* const* d_in, const int* in_sizes, int n_in,
                              void* d_out, int out_size, void* d_ws, size_t ws_size,
                              hipStream_t stream)
{
  const float* x  = (const float*)d_in[0];   // [2,2048,1024]
  const float* gw = (const float*)d_in[1];   // [8,1024]
  const float* w1 = (const float*)d_in[2];   // [8,1024,2048]
  const float* w2 = (const float*)d_in[3];   // [8,2048,1024]
  float* out    = (float*)d_out;
  float* logits = out + (size_t)Tt * Dd;

  int*   meta = (int*)d_ws;                       // 64 ints
  int*   list = (int*)((char*)d_ws + 256);        // 8192 ints
  float* wgt  = (float*)((char*)d_ws + 256 + 32768);
  u16*   xb   = (u16*)((char*)d_ws + 262144);                         // 8 MB
  u16*   h1   = (u16*)((char*)d_ws + 262144 + 8388608);               // 32 MB
  u16*   wT   = (u16*)((char*)d_ws + 262144 + 8388608 + 33554432);    // 33.5 MB
  const size_t NEED = 262144ull + 8388608ull + 33554432ull + 33554432ull;

  router_kernel<<<Tt / 4, 256, 0, stream>>>(x, gw, logits);

  if (ws_size >= NEED) {
    hipMemsetAsync(out, 0, (size_t)Tt * Dd * sizeof(float), stream);
    build_kernel<<<1, 256, 0, stream>>>(logits, meta, list, wgt);
    cvt_bf16_kernel<<<(Tt * Dd / 4) / 256, 256, 0, stream>>>(x, xb, Tt * Dd / 4);
    transpose_bf16_kernel<<<dim3(Ff/64, Dd/64, Ee), 256, 0, stream>>>(w1, wT, Dd, Ff);
    gemm_g<0, Ff, Dd><<<dim3(Ff/128, 32, 8), 256, 0, stream>>>(xb, wT, h1, meta, list, wgt);
    transpose_bf16_kernel<<<dim3(Dd/64, Ff/64, Ee), 256, 0, stream>>>(w2, wT, Ff, Dd);
    gemm_g<1, Dd, Ff><<<dim3(Dd/128, 32, 8), 256, 0, stream>>>(h1, wT, out, meta, list, wgt);
  } else {
    float* combine = (float*)d_ws;
    float* h1d     = combine + (size_t)Tt * Ee;
    combine_kernel<<<Tt / 256, 256, 0, stream>>>(logits, combine);
    size_t cb = (size_t)Tt * Ee * sizeof(float);
    size_t avail = ws_size > cb ? (ws_size - cb) : 0;
    long maxrows = (long)(avail / ((size_t)Ff * sizeof(float)));
    int chunk = (maxrows >= Tt) ? Tt : (int)((maxrows / 128) * 128);
    if (chunk < 128) chunk = 128;
    for (int c0 = 0; c0 < Tt; c0 += chunk) {
      int rows = (Tt - c0) < chunk ? (Tt - c0) : chunk;
      for (int e = 0; e < Ee; ++e) {
        gemm_dense<0, Ff, Dd><<<dim3(Ff/128, rows/128), 256, 0, stream>>>(
            x + (size_t)c0 * Dd, w1 + (size_t)e * Dd * Ff, h1d, nullptr, e, 0);
        gemm_dense<1, Dd, Ff><<<dim3(Dd/128, rows/128), 256, 0, stream>>>(
            h1d, w2 + (size_t)e * Ff * Dd, out + (size_t)c0 * Dd,
            combine + (size_t)c0 * Ee, e, (e == 0) ? 1 : 0);
      }
    }
  }
}